// Round 6
// baseline (217.999 us; speedup 1.0000x reference)
//
#include <hip/hip_runtime.h>
#include <math.h>

namespace {
constexpr int Bc = 4, Sc = 4096, Dc = 768, Gc = 64, Wc = 16, Rc = 4;
constexpr int NWc = Sc / Wc;          // 256 windows per batch row
constexpr int KEEPc = Wc - Rc;        // 12 kept tokens per window
constexpr int Ec = Wc - 1;            // 15 adjacent edges
constexpr int NQc = Dc / 4;           // 192 float4 per x row
constexpr size_t X_ELEMS = (size_t)Bc * NWc * KEEPc * Dc;
constexpr size_t S_ELEMS = (size_t)Bc * NWc * KEEPc * Sc;
constexpr int NROWS = Bc * NWc * KEEPc;                    // 12288 output rows

typedef float vf4 __attribute__((ext_vector_type(4)));
}

// ---- K1: GEMM g=xw@Wg + greedy selection + x_out + p_out + meta ----
// One block per window; 4 waves split K=768; lane = G-column.
__global__ __launch_bounds__(256, 4)
void tm_select(const float* __restrict__ x, const int* __restrict__ pos,
               const float* __restrict__ Wg, float* __restrict__ out,
               int* __restrict__ meta) {
  const int wid = blockIdx.x;          // 0..1023
  const int b = wid >> 8;
  const int n = wid & (NWc - 1);
  const int tid = threadIdx.x;
  const int lane = tid & 63;
  const int wq = tid >> 6;

  const float4* xr4 = reinterpret_cast<const float4*>(x + (size_t)(b * Sc + n * Wc) * Dc);

  float acc[Wc];
#pragma unroll
  for (int w = 0; w < Wc; ++w) acc[w] = 0.f;

  const int q0 = wq * (NQc / 4);       // 48 float4-steps per wave
  for (int q = 0; q < NQc / 4; ++q) {
    const int d4 = q0 + q;
    const int d = d4 * 4;
    const float w0 = Wg[(size_t)d * Gc + lane];
    const float w1 = Wg[(size_t)(d + 1) * Gc + lane];
    const float w2 = Wg[(size_t)(d + 2) * Gc + lane];
    const float w3 = Wg[(size_t)(d + 3) * Gc + lane];
#pragma unroll
    for (int w = 0; w < Wc; ++w) {
      const float4 xv = xr4[w * NQc + d4];               // wave-broadcast 16B
      acc[w] = fmaf(xv.x, w0, acc[w]);
      acc[w] = fmaf(xv.y, w1, acc[w]);
      acc[w] = fmaf(xv.z, w2, acc[w]);
      acc[w] = fmaf(xv.w, w3, acc[w]);
    }
  }

  __shared__ float part[4][Wc][64];    // 16 KiB
#pragma unroll
  for (int w = 0; w < Wc; ++w) part[wq][w][lane] = acc[w];
  __syncthreads();

  float red[Wc + Ec];
  {
    float g[Wc];
#pragma unroll
    for (int w = 0; w < Wc; ++w)
      g[w] = part[0][w][lane] + part[1][w][lane] + part[2][w][lane] + part[3][w][lane];
#pragma unroll
    for (int w = 0; w < Wc; ++w) red[w] = g[w] * g[w];
#pragma unroll
    for (int e = 0; e < Ec; ++e) red[Wc + e] = g[e] * g[e + 1];
  }
#pragma unroll
  for (int m = 1; m < 64; m <<= 1) {
#pragma unroll
    for (int i = 0; i < Wc + Ec; ++i) red[i] += __shfl_xor(red[i], m, 64);
  }

  float nr[Wc];
#pragma unroll
  for (int w = 0; w < Wc; ++w) nr[w] = sqrtf(red[w]);

  float sv[Ec];
#pragma unroll
  for (int e = 0; e < Ec; ++e)
    sv[e] = red[Wc + e] / (fmaxf(nr[e], 1e-12f) * fmaxf(nr[e + 1], 1e-12f));

  unsigned sel = 0, used = 0;
#pragma unroll
  for (int round = 0; round < Rc; ++round) {
    float best = -1e30f;
    int bi = 0;
#pragma unroll
    for (int e = 0; e < Ec; ++e) {
      const bool ok = ((used >> e) & 3u) == 0u;
      const float v = ok ? sv[e] : -1e30f;
      if (v > best) { best = v; bi = e; }   // strict > => smallest index wins ties
    }
    sel |= (1u << bi);
    used |= (3u << bi);
  }

  // ---- x_out: 3 kept rows per wave ----
#pragma unroll
  for (int j3 = 0; j3 < 3; ++j3) {
    const int k = wq * 3 + j3;
    int w = 0, c = 0;
#pragma unroll
    for (int t = 0; t < Wc; ++t) {
      const bool kept = (t == 0) || (((sel >> (t - 1)) & 1u) == 0u);
      if (kept && c == k) w = t;
      c += kept ? 1 : 0;
    }
    const bool mg = (w < Ec) && (((sel >> w) & 1u) != 0u);
    float wi = 0.f, wj = 0.f;
#pragma unroll
    for (int t = 0; t < Wc; ++t) {
      wi = (t == w) ? nr[t] : wi;
      wj = (t == (w + 1)) ? nr[t] : wj;
    }
    float aS = 1.f, bS = 0.f;
    if (mg) {
      const float tot = wi + wj + 1e-8f;
      aS = wi / tot;
      bS = wj / tot;
    }
    const float4* r1 = xr4 + (size_t)w * NQc;
    const float4* r2 = xr4 + (size_t)(mg ? (w + 1) : w) * NQc;
    float4* o = reinterpret_cast<float4*>(out + (size_t)(wid * KEEPc + k) * Dc);
#pragma unroll
    for (int it = 0; it < 3; ++it) {
      const int i = lane + 64 * it;
      const float4 a = r1[i];
      const float4 bb = r2[i];
      float4 rr;
      rr.x = fmaf(aS, a.x, bS * bb.x);
      rr.y = fmaf(aS, a.y, bS * bb.y);
      rr.z = fmaf(aS, a.z, bS * bb.z);
      rr.w = fmaf(aS, a.w, bS * bb.w);
      o[i] = rr;
    }
  }

  // ---- meta + p_out ----
  if (wq == 0 && lane < KEEPc) {
    const int k = lane;
    int w = 0, c = 0;
#pragma unroll
    for (int t = 0; t < Wc; ++t) {
      const bool kept = (t == 0) || (((sel >> (t - 1)) & 1u) == 0u);
      if (kept && c == k) w = t;
      c += kept ? 1 : 0;
    }
    const bool mg = (w < Ec) && (((sel >> w) & 1u) != 0u);
    const int row = wid * KEEPc + k;
    meta[row] = w | (mg ? 16 : 0);
    out[X_ELEMS + S_ELEMS + (size_t)row] = (float)pos[b * Sc + n * Wc + w];
  }
}

// ---- K2: one WAVE per s-row; 2 chunks of 8 independent float4 in flight ----
// 3072 blocks x 256 threads (4 waves). Plain loads/stores, uniform branch.
__global__ __launch_bounds__(256)
void tm_srows(const float* __restrict__ src, const int* __restrict__ meta,
              float* __restrict__ outs) {
  const int row = blockIdx.x * 4 + (threadIdx.x >> 6);   // 0..12287
  const int lane = threadIdx.x & 63;

  const int mt = meta[row];                // wave-uniform -> scalar load
  const int w = mt & 15;
  const bool mg = (mt & 16) != 0;

  const int b = row / (NWc * KEEPc);
  const int m = row - b * (NWc * KEEPc);
  const int n = m / KEEPc;

  const vf4* p1 = reinterpret_cast<const vf4*>(src + (size_t)(b * Sc + n * Wc + w) * Sc);
  vf4* o = reinterpret_cast<vf4*>(outs + (size_t)row * Sc);

  if (mg) {
    const vf4* p2 = p1 + (Sc / 4);
#pragma unroll
    for (int c = 0; c < 2; ++c) {
      vf4 v[8], u[8];
#pragma unroll
      for (int j = 0; j < 8; ++j) v[j] = p1[lane + 64 * (8 * c + j)];
#pragma unroll
      for (int j = 0; j < 8; ++j) u[j] = p2[lane + 64 * (8 * c + j)];
#pragma unroll
      for (int j = 0; j < 8; ++j) o[lane + 64 * (8 * c + j)] = v[j] + u[j];
    }
  } else {
#pragma unroll
    for (int c = 0; c < 2; ++c) {
      vf4 v[8];
#pragma unroll
      for (int j = 0; j < 8; ++j) v[j] = p1[lane + 64 * (8 * c + j)];
#pragma unroll
      for (int j = 0; j < 8; ++j) o[lane + 64 * (8 * c + j)] = v[j];
    }
  }
}

extern "C" void kernel_launch(void* const* d_in, const int* in_sizes, int n_in,
                              void* d_out, int out_size, void* d_ws, size_t ws_size,
                              hipStream_t stream) {
  const float* x = (const float*)d_in[0];
  const float* src = (const float*)d_in[1];
  const int* pos = (const int*)d_in[2];
  const float* Wg = (const float*)d_in[3];
  float* out = (float*)d_out;
  int* meta = (int*)d_ws;

  tm_select<<<dim3(Bc * NWc), dim3(256), 0, stream>>>(x, pos, Wg, out, meta);
  tm_srows<<<dim3(NROWS / 4), dim3(256), 0, stream>>>(src, meta, out + X_ELEMS);
}

// Round 7
// 143.061 us; speedup vs baseline: 1.5238x; 1.5238x over previous
//
#include <hip/hip_runtime.h>
#include <math.h>

namespace {
constexpr int Bc = 4, Sc = 4096, Dc = 768, Gc = 64, Wc = 16, Rc = 4;
constexpr int NWc = Sc / Wc;          // 256 windows per batch row
constexpr int KEEPc = Wc - Rc;        // 12 kept tokens per window
constexpr int Ec = Wc - 1;            // 15 adjacent edges
constexpr int NQc = Dc / 4;           // 192 float4 per x row
constexpr size_t X_ELEMS = (size_t)Bc * NWc * KEEPc * Dc;
constexpr size_t S_ELEMS = (size_t)Bc * NWc * KEEPc * Sc;
constexpr int NROWS = Bc * NWc * KEEPc;                    // 12288 output rows

typedef float vf4 __attribute__((ext_vector_type(4)));
}

// ---- K1: LDS-staged GEMM g=xw@Wg + greedy selection + x_out + p_out + meta
// One block per window; x window (48 KB) staged coalesced into LDS once;
// GEMM reads LDS broadcasts; x_out written from LDS (no global re-read).
__global__ __launch_bounds__(256)
void tm_select(const float* __restrict__ x, const int* __restrict__ pos,
               const float* __restrict__ Wg, float* __restrict__ out,
               int* __restrict__ meta) {
  const int wid = blockIdx.x;          // 0..1023
  const int b = wid >> 8;
  const int n = wid & (NWc - 1);
  const int tid = threadIdx.x;
  const int lane = tid & 63;
  const int wq = tid >> 6;

  __shared__ float4 xs[Wc * NQc];      // 48 KiB: the x window
  __shared__ float part[4][Wc][64];    // 16 KiB: GEMM partials

  const size_t winTok = (size_t)(b * Sc + n * Wc);
  const float4* xg = reinterpret_cast<const float4*>(x + winTok * Dc);

  // stage: 3072 float4, 12 per thread, fully coalesced & independent
#pragma unroll
  for (int i = 0; i < 12; ++i) xs[tid + 256 * i] = xg[tid + 256 * i];
  __syncthreads();

  // GEMM: wave wq handles K-slice [192*wq, 192*wq+192); lane = G-column
  float acc[Wc];
#pragma unroll
  for (int w = 0; w < Wc; ++w) acc[w] = 0.f;
  const int q0 = wq * (NQc / 4);
  for (int q = 0; q < NQc / 4; ++q) {
    const int d4 = q0 + q;
    const int d = d4 * 4;
    const float w0 = Wg[(size_t)d * Gc + lane];          // coalesced, L2-hot
    const float w1 = Wg[(size_t)(d + 1) * Gc + lane];
    const float w2 = Wg[(size_t)(d + 2) * Gc + lane];
    const float w3 = Wg[(size_t)(d + 3) * Gc + lane];
#pragma unroll
    for (int w = 0; w < Wc; ++w) {
      const float4 xv = xs[w * NQc + d4];                // LDS broadcast: free
      acc[w] = fmaf(xv.x, w0, acc[w]);
      acc[w] = fmaf(xv.y, w1, acc[w]);
      acc[w] = fmaf(xv.z, w2, acc[w]);
      acc[w] = fmaf(xv.w, w3, acc[w]);
    }
  }
#pragma unroll
  for (int w = 0; w < Wc; ++w) part[wq][w][lane] = acc[w];
  __syncthreads();

  // reduce norms^2 (16) + adjacent dots (15); all lanes/waves end identical
  float red[Wc + Ec];
  {
    float g[Wc];
#pragma unroll
    for (int w = 0; w < Wc; ++w)
      g[w] = part[0][w][lane] + part[1][w][lane] + part[2][w][lane] + part[3][w][lane];
#pragma unroll
    for (int w = 0; w < Wc; ++w) red[w] = g[w] * g[w];
#pragma unroll
    for (int e = 0; e < Ec; ++e) red[Wc + e] = g[e] * g[e + 1];
  }
#pragma unroll
  for (int m = 1; m < 64; m <<= 1) {
#pragma unroll
    for (int i = 0; i < Wc + Ec; ++i) red[i] += __shfl_xor(red[i], m, 64);
  }

  float nr[Wc];
#pragma unroll
  for (int w = 0; w < Wc; ++w) nr[w] = sqrtf(red[w]);

  float sv[Ec];
#pragma unroll
  for (int e = 0; e < Ec; ++e)
    sv[e] = red[Wc + e] / (fmaxf(nr[e], 1e-12f) * fmaxf(nr[e + 1], 1e-12f));

  unsigned sel = 0, used = 0;
#pragma unroll
  for (int round = 0; round < Rc; ++round) {
    float best = -1e30f;
    int bi = 0;
#pragma unroll
    for (int e = 0; e < Ec; ++e) {
      const bool ok = ((used >> e) & 3u) == 0u;
      const float v = ok ? sv[e] : -1e30f;
      if (v > best) { best = v; bi = e; }   // strict > => smallest index wins ties
    }
    sel |= (1u << bi);
    used |= (3u << bi);
  }

  // x_out: 3 kept rows per wave, sourced from LDS
#pragma unroll
  for (int j3 = 0; j3 < 3; ++j3) {
    const int k = wq * 3 + j3;
    int w = 0, c = 0;
#pragma unroll
    for (int t = 0; t < Wc; ++t) {
      const bool kept = (t == 0) || (((sel >> (t - 1)) & 1u) == 0u);
      if (kept && c == k) w = t;
      c += kept ? 1 : 0;
    }
    const bool mg = (w < Ec) && (((sel >> w) & 1u) != 0u);
    float wi = 0.f, wj = 0.f;
#pragma unroll
    for (int t = 0; t < Wc; ++t) {
      wi = (t == w) ? nr[t] : wi;
      wj = (t == (w + 1)) ? nr[t] : wj;
    }
    float aS = 1.f, bS = 0.f;
    if (mg) {
      const float tot = wi + wj + 1e-8f;
      aS = wi / tot;
      bS = wj / tot;
    }
    const float4* r1 = &xs[w * NQc];
    const float4* r2 = &xs[(mg ? (w + 1) : w) * NQc];
    vf4* o = reinterpret_cast<vf4*>(out + (size_t)(wid * KEEPc + k) * Dc);
#pragma unroll
    for (int it = 0; it < 3; ++it) {
      const int i = lane + 64 * it;
      const float4 a = r1[i];
      const float4 bb = r2[i];
      vf4 rr;
      rr.x = fmaf(aS, a.x, bS * bb.x);
      rr.y = fmaf(aS, a.y, bS * bb.y);
      rr.z = fmaf(aS, a.z, bS * bb.z);
      rr.w = fmaf(aS, a.w, bS * bb.w);
      __builtin_nontemporal_store(rr, o + i);
    }
  }

  // meta + p_out
  if (wq == 0 && lane < KEEPc) {
    const int k = lane;
    int w = 0, c = 0;
#pragma unroll
    for (int t = 0; t < Wc; ++t) {
      const bool kept = (t == 0) || (((sel >> (t - 1)) & 1u) == 0u);
      if (kept && c == k) w = t;
      c += kept ? 1 : 0;
    }
    const bool mg = (w < Ec) && (((sel >> w) & 1u) != 0u);
    const int row = wid * KEEPc + k;
    meta[row] = w | (mg ? 16 : 0);
    out[X_ELEMS + S_ELEMS + (size_t)row] = (float)pos[winTok + w];
  }
}

// ---- K2: s-rows only. One 1024-thread block per output row, 1 f4/thread ----
__global__ __launch_bounds__(1024)
void tm_srows(const float* __restrict__ src, const int* __restrict__ meta,
              float* __restrict__ outs) {
  const int gid = blockIdx.x;              // 0..12287
  const int t = threadIdx.x;

  const int mt = meta[gid];                // block-uniform
  const int w = mt & 15;
  const bool mg = (mt & 16) != 0;

  const int b = gid / (NWc * KEEPc);
  const int m = gid - b * (NWc * KEEPc);
  const int n = m / KEEPc;

  const vf4* s1 = reinterpret_cast<const vf4*>(src + (size_t)(b * Sc + n * Wc + w) * Sc);
  vf4 a = s1[t];
  if (mg) a = a + s1[t + (Sc / 4)];
  __builtin_nontemporal_store(a, reinterpret_cast<vf4*>(outs + (size_t)gid * Sc) + t);
}

extern "C" void kernel_launch(void* const* d_in, const int* in_sizes, int n_in,
                              void* d_out, int out_size, void* d_ws, size_t ws_size,
                              hipStream_t stream) {
  const float* x = (const float*)d_in[0];
  const float* src = (const float*)d_in[1];
  const int* pos = (const int*)d_in[2];
  const float* Wg = (const float*)d_in[3];
  float* out = (float*)d_out;
  int* meta = (int*)d_ws;

  tm_select<<<dim3(Bc * NWc), dim3(256), 0, stream>>>(x, pos, Wg, out, meta);
  tm_srows<<<dim3(NROWS), dim3(1024), 0, stream>>>(src, meta, out + X_ELEMS);
}

// Round 9
// 117.672 us; speedup vs baseline: 1.8526x; 1.2158x over previous
//
#include <hip/hip_runtime.h>
#include <math.h>

namespace {
constexpr int Bc = 4, Sc = 4096, Dc = 768, Gc = 64, Wc = 16, Rc = 4;
constexpr int NWc = Sc / Wc;          // 256 windows per batch row
constexpr int KEEPc = Wc - Rc;        // 12 kept tokens per window
constexpr int Ec = Wc - 1;            // 15 adjacent edges
constexpr int NQc = Dc / 4;           // 192 float4 per x row
constexpr int PQ = NQc + 1;           // padded LDS row stride (f4)
constexpr size_t X_ELEMS = (size_t)Bc * NWc * KEEPc * Dc;
constexpr size_t S_ELEMS = (size_t)Bc * NWc * KEEPc * Sc;
constexpr int NROWS = Bc * NWc * KEEPc;                    // 12288 output rows

typedef float vf4 __attribute__((ext_vector_type(4)));
typedef float f32x4 __attribute__((ext_vector_type(4)));
typedef short bf16x8 __attribute__((ext_vector_type(8)));

__device__ inline short f2bf(float f) {      // native HW cvt, compiler packs pairs
  return __builtin_bit_cast(short, (__bf16)f);
}
}

// ---- K1: MFMA gating GEMM + greedy selection + x_out + p_out + meta ----
// One block per window. Stage x (48KB, padded) into LDS; wave wq computes
// g columns [16wq,16wq+16) via 24x builtin mfma_f32_16x16x32_bf16; g -> LDS;
// all waves redundantly reduce+select; x_out written from LDS.
__global__ __launch_bounds__(256)
void tm_select(const float* __restrict__ x, const int* __restrict__ pos,
               const float* __restrict__ Wg, float* __restrict__ out,
               int* __restrict__ meta) {
  const int wid = blockIdx.x;          // 0..1023
  const int b = wid >> 8;
  const int n = wid & (NWc - 1);
  const int tid = threadIdx.x;
  const int lane = tid & 63;
  const int wq = tid >> 6;

  __shared__ float4 xs4[Wc * PQ];      // ~49 KB, padded rows
  __shared__ float gl[Wc][Gc];         // 4 KB: g = x @ Wg

  const size_t winTok = (size_t)(b * Sc + n * Wc);
  const float4* xg = reinterpret_cast<const float4*>(x + winTok * Dc);

  // stage x: 3072 f4, 12/thread, coalesced reads, padded LDS rows
#pragma unroll
  for (int i = 0; i < 12; ++i) {
    const int idx = tid + 256 * i;
    const int r = idx / NQc;
    const int c = idx - r * NQc;
    xs4[r * PQ + c] = xg[idx];
  }
  __syncthreads();

  // ---- MFMA GEMM: A[row][k]=x, B[k][col]=Wg; wave wq owns g-cols 16wq.. ----
  const int arow = lane & 15;          // A row == C col (within tile)
  const int kg = lane >> 4;            // 0..3
  const int col = 16 * wq + arow;      // global Wg/g column
  f32x4 cacc = {0.f, 0.f, 0.f, 0.f};

  for (int s = 0; s < 24; ++s) {
    const float4 a0 = xs4[arow * PQ + s * 8 + kg * 2];
    const float4 a1 = xs4[arow * PQ + s * 8 + kg * 2 + 1];
    bf16x8 af;
    af[0] = f2bf(a0.x); af[1] = f2bf(a0.y); af[2] = f2bf(a0.z); af[3] = f2bf(a0.w);
    af[4] = f2bf(a1.x); af[5] = f2bf(a1.y); af[6] = f2bf(a1.z); af[7] = f2bf(a1.w);
    const int kbase = s * 32 + kg * 8;
    bf16x8 bf;
#pragma unroll
    for (int j = 0; j < 8; ++j) bf[j] = f2bf(Wg[(size_t)(kbase + j) * Gc + col]);
    cacc = __builtin_amdgcn_mfma_f32_16x16x32_bf16(af, bf, cacc, 0, 0, 0);
  }

  // C layout (m89-verified): lane holds col=lane&15, rows kg*4+r
#pragma unroll
  for (int r = 0; r < 4; ++r) gl[kg * 4 + r][col] = cacc[r];
  __syncthreads();

  // ---- reduce norms^2 (16) + adjacent dots (15); all lanes end identical ----
  float red[Wc + Ec];
  {
    float g[Wc];
#pragma unroll
    for (int w = 0; w < Wc; ++w) g[w] = gl[w][lane];
#pragma unroll
    for (int w = 0; w < Wc; ++w) red[w] = g[w] * g[w];
#pragma unroll
    for (int e = 0; e < Ec; ++e) red[Wc + e] = g[e] * g[e + 1];
  }
#pragma unroll
  for (int m = 1; m < 64; m <<= 1) {
#pragma unroll
    for (int i = 0; i < Wc + Ec; ++i) red[i] += __shfl_xor(red[i], m, 64);
  }

  float nr[Wc];
#pragma unroll
  for (int w = 0; w < Wc; ++w) nr[w] = sqrtf(red[w]);

  float sv[Ec];
#pragma unroll
  for (int e = 0; e < Ec; ++e)
    sv[e] = red[Wc + e] / (fmaxf(nr[e], 1e-12f) * fmaxf(nr[e + 1], 1e-12f));

  unsigned sel = 0, used = 0;
#pragma unroll
  for (int round = 0; round < Rc; ++round) {
    float best = -1e30f;
    int bi = 0;
#pragma unroll
    for (int e = 0; e < Ec; ++e) {
      const bool ok = ((used >> e) & 3u) == 0u;
      const float v = ok ? sv[e] : -1e30f;
      if (v > best) { best = v; bi = e; }   // strict > => smallest index wins ties
    }
    sel |= (1u << bi);
    used |= (3u << bi);
  }

  // ---- x_out: 3 kept rows per wave, sourced from (padded) LDS ----
#pragma unroll
  for (int j3 = 0; j3 < 3; ++j3) {
    const int k = wq * 3 + j3;
    int w = 0, c = 0;
#pragma unroll
    for (int t = 0; t < Wc; ++t) {
      const bool kept = (t == 0) || (((sel >> (t - 1)) & 1u) == 0u);
      if (kept && c == k) w = t;
      c += kept ? 1 : 0;
    }
    const bool mg = (w < Ec) && (((sel >> w) & 1u) != 0u);
    float wi = 0.f, wj = 0.f;
#pragma unroll
    for (int t = 0; t < Wc; ++t) {
      wi = (t == w) ? nr[t] : wi;
      wj = (t == (w + 1)) ? nr[t] : wj;
    }
    float aS = 1.f, bS = 0.f;
    if (mg) {
      const float tot = wi + wj + 1e-8f;
      aS = wi / tot;
      bS = wj / tot;
    }
    const float4* r1 = &xs4[w * PQ];
    const float4* r2 = &xs4[(mg ? (w + 1) : w) * PQ];
    vf4* o = reinterpret_cast<vf4*>(out + (size_t)(wid * KEEPc + k) * Dc);
#pragma unroll
    for (int it = 0; it < 3; ++it) {
      const int i = lane + 64 * it;
      const float4 a = r1[i];
      const float4 bb = r2[i];
      vf4 rr;
      rr.x = fmaf(aS, a.x, bS * bb.x);
      rr.y = fmaf(aS, a.y, bS * bb.y);
      rr.z = fmaf(aS, a.z, bS * bb.z);
      rr.w = fmaf(aS, a.w, bS * bb.w);
      __builtin_nontemporal_store(rr, o + i);
    }
  }

  // ---- meta + p_out ----
  if (wq == 0 && lane < KEEPc) {
    const int k = lane;
    int w = 0, c = 0;
#pragma unroll
    for (int t = 0; t < Wc; ++t) {
      const bool kept = (t == 0) || (((sel >> (t - 1)) & 1u) == 0u);
      if (kept && c == k) w = t;
      c += kept ? 1 : 0;
    }
    const bool mg = (w < Ec) && (((sel >> w) & 1u) != 0u);
    const int row = wid * KEEPc + k;
    meta[row] = w | (mg ? 16 : 0);
    out[X_ELEMS + S_ELEMS + (size_t)row] = (float)pos[winTok + w];
  }
}

// ---- K2: s-rows only. One 1024-thread block per output row, 1 f4/thread ----
__global__ __launch_bounds__(1024)
void tm_srows(const float* __restrict__ src, const int* __restrict__ meta,
              float* __restrict__ outs) {
  const int gid = blockIdx.x;              // 0..12287
  const int t = threadIdx.x;

  const int mt = meta[gid];                // block-uniform
  const int w = mt & 15;
  const bool mg = (mt & 16) != 0;

  const int b = gid / (NWc * KEEPc);
  const int m = gid - b * (NWc * KEEPc);
  const int n = m / KEEPc;

  const vf4* s1 = reinterpret_cast<const vf4*>(src + (size_t)(b * Sc + n * Wc + w) * Sc);
  vf4 a = s1[t];
  if (mg) a = a + s1[t + (Sc / 4)];
  __builtin_nontemporal_store(a, reinterpret_cast<vf4*>(outs + (size_t)gid * Sc) + t);
}

extern "C" void kernel_launch(void* const* d_in, const int* in_sizes, int n_in,
                              void* d_out, int out_size, void* d_ws, size_t ws_size,
                              hipStream_t stream) {
  const float* x = (const float*)d_in[0];
  const float* src = (const float*)d_in[1];
  const int* pos = (const int*)d_in[2];
  const float* Wg = (const float*)d_in[3];
  float* out = (float*)d_out;
  int* meta = (int*)d_ws;

  tm_select<<<dim3(Bc * NWc), dim3(256), 0, stream>>>(x, pos, Wg, out, meta);
  tm_srows<<<dim3(NROWS), dim3(1024), 0, stream>>>(src, meta, out + X_ELEMS);
}